// Round 7
// baseline (294.359 us; speedup 1.0000x reference)
//
#include <hip/hip_runtime.h>
#include <stdint.h>

// SparseAttentionAggregator: B=4 H=16 S=2048 D=64, fp32 in/out, mask [B,S,S] int32
// out = softmax((Q K^T)/8 masked_fill(mask==0,-1e9)) V
//
// R7: (1) LUT masking — acc init is plain NC; masked P zeroed on packed bf16
// via AND with a 16-entry LDS LUT (replaces 13-instr cndmask chain with 4 VALU
// + 1 ds_read_b64). (2) g=4: 64 q-rows/wave, grid 512 — halves device DS frag
// traffic (fragment reads amortized over 2x Q); async global_load_lds staging
// keeps loads off the critical path. VGPR ~170 @ 2 blocks/CU.

#define SQ 2048
#define DD 64

typedef __attribute__((ext_vector_type(8))) short short8;   // 8 bf16
typedef __attribute__((ext_vector_type(4))) short bshort4;  // 4 bf16
typedef __attribute__((ext_vector_type(4))) float f32x4;

union U8 { uint32_t u[4]; short8 s; };
union U4 { uint32_t u[2]; bshort4 s; };

__device__ __forceinline__ uint32_t pk_rne(float lo, float hi) {
  uint32_t a = __builtin_bit_cast(uint32_t, lo) + 0x8000u;
  uint32_t b = __builtin_bit_cast(uint32_t, hi) + 0x8000u;
  return __builtin_amdgcn_perm(b, a, 0x07060302u);
}
__device__ __forceinline__ uint32_t pk_tr(float lo, float hi) {
  return __builtin_amdgcn_perm(__builtin_bit_cast(uint32_t, hi),
                               __builtin_bit_cast(uint32_t, lo), 0x07060302u);
}

#if __has_builtin(__builtin_amdgcn_exp2f)
#define EXP2(x) __builtin_amdgcn_exp2f(x)
#else
#define EXP2(x) __exp2f(x)
#endif

__device__ __forceinline__ f32x4 mfma32(short8 a, short8 b, f32x4 c) {
  return __builtin_amdgcn_mfma_f32_16x16x32_bf16(a, b, c, 0, 0, 0);
}
#if __has_builtin(__builtin_amdgcn_mfma_f32_16x16x16bf16_1k)
__device__ __forceinline__ f32x4 mfma16(bshort4 a, bshort4 b, f32x4 c) {
  return __builtin_amdgcn_mfma_f32_16x16x16bf16_1k(a, b, c, 0, 0, 0);
}
#else
__device__ __forceinline__ f32x4 mfma16(bshort4 a, bshort4 b, f32x4 c) {
  asm("v_mfma_f32_16x16x16_bf16 %0, %1, %2, %0" : "+v"(c) : "v"(a), "v"(b));
  return c;
}
#endif

// async 16B/lane global->LDS; dest = base + lane*16
__device__ __forceinline__ void gload_lds16(const short* g, short* l) {
  __builtin_amdgcn_global_load_lds(
      (const __attribute__((address_space(1))) uint32_t*)g,
      (__attribute__((address_space(3))) uint32_t*)l, 16, 0, 0);
}

// ---- prep: mask bits (coalesced + ballot) ----
__global__ __launch_bounds__(256) void pack_mask_kernel(const int* __restrict__ m,
                                                        uint32_t* __restrict__ bits) {
  const int lane = threadIdx.x & 63;
  const int wid = (blockIdx.x * 256 + threadIdx.x) >> 6;
  const int nw = (gridDim.x * 256) >> 6;
  const size_t total = (size_t)4 * SQ * SQ;
  for (size_t base = (size_t)wid * 64; base < total; base += (size_t)nw * 64) {
    int v = m[base + lane];
    unsigned long long b = __ballot(v != 0);
    if (lane == 0) *(unsigned long long*)&bits[base >> 5] = b;
  }
}

// ---- prep: K -> fragment-ordered bf16 tiles (1,048,576 threads) ----
__global__ __launch_bounds__(256) void prep_k_kernel(const float* __restrict__ K,
                                                     short* __restrict__ Kt) {
  int tid = blockIdx.x * 256 + threadIdx.x;
  int l = tid & 63, rk = (tid >> 6) & 7, kt = (tid >> 9) & 31, bh = tid >> 14;
  if (bh >= 64) return;
  int key = kt * 64 + (rk >> 1) * 16 + (l & 15);
  int d0 = (rk & 1) * 32 + (l >> 4) * 8;
  const float* src = K + (size_t)bh * (SQ * DD) + (size_t)key * DD + d0;
  float4 a = ((const float4*)src)[0];
  float4 c = ((const float4*)src)[1];
  U8 w;
  w.u[0] = pk_rne(a.x, a.y); w.u[1] = pk_rne(a.z, a.w);
  w.u[2] = pk_rne(c.x, c.y); w.u[3] = pk_rne(c.z, c.w);
  *(short8*)(Kt + (size_t)tid * 8) = w.s;
}

// ---- prep: V^T -> fragment-ordered bf16 tiles (2,097,152 threads) ----
__global__ __launch_bounds__(256) void prep_v_kernel(const float* __restrict__ V,
                                                     short* __restrict__ Vt) {
  int tid = blockIdx.x * 256 + threadIdx.x;
  int r = tid & 63, rv = (tid >> 6) & 15, kt = (tid >> 10) & 31, bh = tid >> 15;
  if (bh >= 64) return;
  int d = (rv & 3) * 16 + (r & 15);
  int k0 = kt * 64 + (rv >> 2) * 16 + (r >> 4) * 4;
  const float* s = V + (size_t)bh * (SQ * DD) + (size_t)k0 * DD + d;
  U4 w;
  w.u[0] = pk_rne(s[0], s[DD]);
  w.u[1] = pk_rne(s[2 * DD], s[3 * DD]);
  *(bshort4*)(Vt + (size_t)tid * 4) = w.s;
}

// ---- fast attention: g=4, LUT masking, async staging ----
__global__ __launch_bounds__(256, 2) void attn_fast(
    const float* __restrict__ Qg, const short* __restrict__ Kt,
    const short* __restrict__ Vt, const uint32_t* __restrict__ bits,
    float* __restrict__ Og) {
  __shared__ __align__(16) short sK[2][4096];  // 8KB per buf, fragment order
  __shared__ __align__(16) short sV[2][4096];
  __shared__ __align__(8) uint32_t sLut[32];   // 16 x {m_lo, m_hi}

  const int tid = threadIdx.x;
  const int lane = tid & 63;
  const int wv = tid >> 6;
  const int l15 = lane & 15;
  const int quad = lane >> 4;

  const int bid = blockIdx.x;  // (b, qt, h), h innermost
  const int h = bid & 15;
  const int qt = (bid >> 4) & 7;
  const int b = bid >> 7;

  if (tid < 16) {  // mask LUT: bit r of index -> 0xFFFF half-mask
    uint32_t m0 = ((tid & 1) ? 0xFFFFu : 0u) | ((tid & 2) ? 0xFFFF0000u : 0u);
    uint32_t m1 = ((tid & 4) ? 0xFFFFu : 0u) | ((tid & 8) ? 0xFFFF0000u : 0u);
    sLut[tid * 2] = m0;
    sLut[tid * 2 + 1] = m1;
  }

  const size_t bh = (size_t)b * 16 + h;
  const float* Qp = Qg + bh * (size_t)(SQ * DD);
  const short* Kh = Kt + bh * (size_t)(SQ * DD);
  const short* Vh = Vt + bh * (size_t)(SQ * DD);
  float* Op = Og + bh * (size_t)(SQ * DD);
  const int q0w = qt * 256 + wv * 64;  // 64 q-rows/wave (4 groups)
  const int brow = b * SQ;

  const float QS = 0.18033688f;   // 0.125 * log2(e)
  const float NC = -17.312340f;   // -12 * log2(e)
  const f32x4 NCv = {NC, NC, NC, NC};

  U4 onesu; onesu.u[0] = 0x3f803f80u; onesu.u[1] = 0x3f803f80u;
  const bshort4 ones = onesu.s;

  // Q fragments (pre-scaled)
  short8 qf[4][2];
#pragma unroll
  for (int g = 0; g < 4; ++g)
#pragma unroll
    for (int dc = 0; dc < 2; ++dc) {
      const float* src = Qp + (size_t)(q0w + g * 16 + l15) * DD + dc * 32 + quad * 8;
      float4 a = *(const float4*)src;
      float4 c = *(const float4*)(src + 4);
      U8 t;
      t.u[0] = pk_rne(a.x * QS, a.y * QS);
      t.u[1] = pk_rne(a.z * QS, a.w * QS);
      t.u[2] = pk_rne(c.x * QS, c.y * QS);
      t.u[3] = pk_rne(c.z * QS, c.w * QS);
      qf[g][dc] = t.s;
    }

  f32x4 o[4][4];
  f32x4 osum[4];
#pragma unroll
  for (int g = 0; g < 4; ++g) {
#pragma unroll
    for (int dc = 0; dc < 4; ++dc) o[g][dc] = (f32x4){0.f, 0.f, 0.f, 0.f};
    osum[g] = (f32x4){0.f, 0.f, 0.f, 0.f};
  }

  // per-wave staging: 2 K-chunks + 2 V-chunks
  const int rk0 = wv * 2, rk1 = wv * 2 + 1;
  const short* kg0 = Kh + rk0 * 512 + lane * 8;  // +kt*4096 per tile
  const short* kg1 = Kh + rk1 * 512 + lane * 8;
  const short* vg0 = Vh + rk0 * 512 + lane * 8;
  const short* vg1 = Vh + rk1 * 512 + lane * 8;

  uint2 mwc[4], mwn[4];
#pragma unroll
  for (int g = 0; g < 4; ++g)
    mwc[g] = *(const uint2*)&bits[(size_t)(brow + q0w + g * 16 + l15) * (SQ / 32)];

  // prologue: stage tile 0 into buf 0
  gload_lds16(kg0, &sK[0][rk0 * 512]);
  gload_lds16(kg1, &sK[0][rk1 * 512]);
  gload_lds16(vg0, &sV[0][rk0 * 512]);
  gload_lds16(vg1, &sV[0][rk1 * 512]);

  const int sh0 = quad * 4;        // bit offsets for bfe
  const int sh1 = quad * 4 + 16;

  for (int kt = 0; kt < SQ / 64; ++kt) {
    const int buf = kt & 1;

    __syncthreads();  // buf loads complete; buf^1 readers done; sLut visible

    if (kt + 1 < SQ / 64) {  // async-stage next tile into buf^1
      const int off = (kt + 1) * 4096;
      gload_lds16(kg0 + off, &sK[buf ^ 1][rk0 * 512]);
      gload_lds16(kg1 + off, &sK[buf ^ 1][rk1 * 512]);
      gload_lds16(vg0 + off, &sV[buf ^ 1][rk0 * 512]);
      gload_lds16(vg1 + off, &sV[buf ^ 1][rk1 * 512]);
#pragma unroll
      for (int g = 0; g < 4; ++g)
        mwn[g] = *(const uint2*)&bits[(size_t)(brow + q0w + g * 16 + l15) * (SQ / 32) + (kt + 1) * 2];
    }

    const short* kb_base = &sK[buf][lane * 8];   // ds_read_b128 imm offsets
    const short* vb_base = &sV[buf][lane * 4];   // ds_read_b64 imm offsets

#pragma unroll
    for (int kb = 0; kb < 4; ++kb) {
      short8 kfa = *(const short8*)&kb_base[(kb * 2 + 0) * 512];
      short8 kfb = *(const short8*)&kb_base[(kb * 2 + 1) * 512];
      bshort4 vf[4];
#pragma unroll
      for (int dc = 0; dc < 4; ++dc)
        vf[dc] = *(const bshort4*)&vb_base[(kb * 4 + dc) * 256];
      const int sh = (kb & 1) ? sh1 : sh0;

#pragma unroll
      for (int g = 0; g < 4; ++g) {
        uint32_t w = (kb & 2) ? mwc[g].y : mwc[g].x;
        uint32_t t = (w >> sh) & 15u;              // v_bfe
        uint2 msk = *(const uint2*)&sLut[t * 2];   // ds_read_b64
        f32x4 st = mfma32(kfa, qf[g][0], NCv);
        st = mfma32(kfb, qf[g][1], st);
        float p0 = EXP2(st[0]);
        float p1 = EXP2(st[1]);
        float p2 = EXP2(st[2]);
        float p3 = EXP2(st[3]);
        U4 pw;
        pw.u[0] = pk_tr(p0, p1) & msk.x;  // zero masked halves exactly
        pw.u[1] = pk_tr(p2, p3) & msk.y;
#pragma unroll
        for (int dc = 0; dc < 4; ++dc)
          o[g][dc] = mfma16(pw.s, vf[dc], o[g][dc]);
        osum[g] = mfma16(pw.s, ones, osum[g]);
      }
    }

    if (kt + 1 < SQ / 64) {
#pragma unroll
      for (int g = 0; g < 4; ++g) mwc[g] = mwn[g];
    }
  }

  // epilogue: osum C/D layout == store layout; no shuffles
#pragma unroll
  for (int g = 0; g < 4; ++g)
#pragma unroll
    for (int r = 0; r < 4; ++r) {
      float inv = 1.0f / osum[g][r];
      float* dst = Op + (size_t)(q0w + g * 16 + quad * 4 + r) * DD + l15;
      dst[0]  = o[g][0][r] * inv;
      dst[16] = o[g][1][r] * inv;
      dst[32] = o[g][2][r] * inv;
      dst[48] = o[g][3][r] * inv;
    }
}

// ---- fallback (R3-winning structure) for small ws ----
template <bool USE_BITS>
__global__ __launch_bounds__(256, 2) void attn_fb(
    const float* __restrict__ Qg, const float* __restrict__ Kg,
    const float* __restrict__ Vg, const int* __restrict__ Mg,
    const uint32_t* __restrict__ bits, float* __restrict__ Og) {
  __shared__ __align__(16) short sK[2][64 * 72];
  __shared__ __align__(16) short sVT[2][64 * 72];
  const int tid = threadIdx.x;
  const int lane = tid & 63;
  const int wv = tid >> 6;
  const int l15 = lane & 15;
  const int quad = lane >> 4;
  const int bid = blockIdx.x;
  const int h = bid & 15;
  const int qt = (bid >> 4) & 7;
  const int b = bid >> 7;
  const size_t bh = (size_t)b * 16 + h;
  const float* Qp = Qg + bh * (size_t)(SQ * DD);
  const float* Kp = Kg + bh * (size_t)(SQ * DD);
  const float* Vp = Vg + bh * (size_t)(SQ * DD);
  float* Op = Og + bh * (size_t)(SQ * DD);
  const int q0w = qt * 256 + wv * 64;
  const int brow = b * SQ;
  const float QS = 0.18033688f, NC = -17.312340f;
  const float NINF = -__builtin_inff();
  U4 onesu; onesu.u[0] = 0x3f803f80u; onesu.u[1] = 0x3f803f80u;
  const bshort4 ones = onesu.s;
  short8 qf[4][2];
#pragma unroll
  for (int g = 0; g < 4; ++g)
#pragma unroll
    for (int dc = 0; dc < 2; ++dc) {
      const float* src = Qp + (size_t)(q0w + g * 16 + l15) * DD + dc * 32 + quad * 8;
      float4 a = *(const float4*)src;
      float4 c = *(const float4*)(src + 4);
      U8 t;
      t.u[0] = pk_rne(a.x * QS, a.y * QS); t.u[1] = pk_rne(a.z * QS, a.w * QS);
      t.u[2] = pk_rne(c.x * QS, c.y * QS); t.u[3] = pk_rne(c.z * QS, c.w * QS);
      qf[g][dc] = t.s;
    }
  f32x4 o[4][4]; f32x4 osum[4];
#pragma unroll
  for (int g = 0; g < 4; ++g) {
#pragma unroll
    for (int dc = 0; dc < 4; ++dc) o[g][dc] = (f32x4){0.f, 0.f, 0.f, 0.f};
    osum[g] = (f32x4){0.f, 0.f, 0.f, 0.f};
  }
  const int kr = lane, kcb = wv * 16;
  const int vr2 = (lane & 31) * 2, vcb = wv * 16 + (lane >> 5) * 8;
  const float* kbase = Kp + (size_t)kr * DD + kcb;
  const float* vbase = Vp + (size_t)vr2 * DD + vcb;
  float4 kA, kB, kC, kD, vA, vB, vC, vD;
  uint2 mwc[4], mwn[4];
  {
    const float4* kp = (const float4*)kbase;
    kA = kp[0]; kB = kp[1]; kC = kp[2]; kD = kp[3];
    const float* r0 = vbase;
    vA = ((const float4*)r0)[0]; vB = ((const float4*)r0)[1];
    vC = ((const float4*)(r0 + DD))[0]; vD = ((const float4*)(r0 + DD))[1];
    if (USE_BITS) {
#pragma unroll
      for (int g = 0; g < 4; ++g)
        mwc[g] = *(const uint2*)&bits[(size_t)(brow + q0w + g * 16 + l15) * (SQ / 32)];
    }
    U8 w0, w1;
    w0.u[0] = pk_rne(kA.x, kA.y); w0.u[1] = pk_rne(kA.z, kA.w);
    w0.u[2] = pk_rne(kB.x, kB.y); w0.u[3] = pk_rne(kB.z, kB.w);
    w1.u[0] = pk_rne(kC.x, kC.y); w1.u[1] = pk_rne(kC.z, kC.w);
    w1.u[2] = pk_rne(kD.x, kD.y); w1.u[3] = pk_rne(kD.z, kD.w);
    *(short8*)&sK[0][kr * 72 + kcb] = w0.s;
    *(short8*)&sK[0][kr * 72 + kcb + 8] = w1.s;
    float av[8] = {vA.x, vA.y, vA.z, vA.w, vB.x, vB.y, vB.z, vB.w};
    float bv[8] = {vC.x, vC.y, vC.z, vC.w, vD.x, vD.y, vD.z, vD.w};
#pragma unroll
    for (int j = 0; j < 8; ++j)
      *(uint32_t*)&sVT[0][(vcb + j) * 72 + vr2] = pk_rne(av[j], bv[j]);
  }
  for (int kt = 0; kt < SQ / 64; ++kt) {
    const int buf = kt & 1;
    const int k0 = kt * 64;
    __syncthreads();
    if (kt + 1 < SQ / 64) {
      const float4* kp = (const float4*)(kbase + (size_t)(k0 + 64) * DD);
      kA = kp[0]; kB = kp[1]; kC = kp[2]; kD = kp[3];
      const float* r0 = vbase + (size_t)(k0 + 64) * DD;
      vA = ((const float4*)r0)[0]; vB = ((const float4*)r0)[1];
      vC = ((const float4*)(r0 + DD))[0]; vD = ((const float4*)(r0 + DD))[1];
      if (USE_BITS) {
#pragma unroll
        for (int g = 0; g < 4; ++g)
          mwn[g] = *(const uint2*)&bits[(size_t)(brow + q0w + g * 16 + l15) * (SQ / 32) + (kt + 1) * 2];
      }
    }
    const short* sKb = sK[buf];
    const short* sVb = sVT[buf];
#pragma unroll
    for (int kb = 0; kb < 4; ++kb) {
      short8 kfa = *(const short8*)&sKb[(kb * 16 + l15) * 72 + quad * 8];
      short8 kfb = *(const short8*)&sKb[(kb * 16 + l15) * 72 + 32 + quad * 8];
      bshort4 vf[4];
#pragma unroll
      for (int dc = 0; dc < 4; ++dc)
        vf[dc] = *(const bshort4*)&sVb[(dc * 16 + l15) * 72 + kb * 16 + quad * 4];
#pragma unroll
      for (int g = 0; g < 4; ++g) {
        uint32_t t;
        if (USE_BITS) {
          uint32_t w = (kb & 2) ? mwc[g].y : mwc[g].x;
          t = w >> ((kb & 1) * 16 + quad * 4);
        } else {
          const int* mrow = Mg + (size_t)(brow + q0w + g * 16 + l15) * SQ + k0 + kb * 16 + quad * 4;
          t = (mrow[0] != 0) | ((mrow[1] != 0) << 1) | ((mrow[2] != 0) << 2) |
              ((mrow[3] != 0) << 3);
        }
        f32x4 ci;
        ci[0] = (t & 1) ? NC : NINF;
        ci[1] = (t & 2) ? NC : NINF;
        ci[2] = (t & 4) ? NC : NINF;
        ci[3] = (t & 8) ? NC : NINF;
        f32x4 st = mfma32(kfa, qf[g][0], ci);
        st = mfma32(kfb, qf[g][1], st);
        float p0 = EXP2(st[0]), p1 = EXP2(st[1]), p2 = EXP2(st[2]), p3 = EXP2(st[3]);
        U4 pw;
        pw.u[0] = pk_tr(p0, p1);
        pw.u[1] = pk_tr(p2, p3);
#pragma unroll
        for (int dc = 0; dc < 4; ++dc)
          o[g][dc] = mfma16(pw.s, vf[dc], o[g][dc]);
        osum[g] = mfma16(pw.s, ones, osum[g]);
      }
    }
    if (kt + 1 < SQ / 64) {
      short* dK = (short*)sK[buf ^ 1];
      short* dV = (short*)sVT[buf ^ 1];
      U8 w0, w1;
      w0.u[0] = pk_rne(kA.x, kA.y); w0.u[1] = pk_rne(kA.z, kA.w);
      w0.u[2] = pk_rne(kB.x, kB.y); w0.u[3] = pk_rne(kB.z, kB.w);
      w1.u[0] = pk_rne(kC.x, kC.y); w1.u[1] = pk_rne(kC.z, kC.w);
      w1.u[2] = pk_rne(kD.x, kD.y); w1.u[3] = pk_rne(kD.z, kD.w);
      *(short8*)&dK[kr * 72 + kcb] = w0.s;
      *(short8*)&dK[kr * 72 + kcb + 8] = w1.s;
      float av[8] = {vA.x, vA.y, vA.z, vA.w, vB.x, vB.y, vB.z, vB.w};
      float bv[8] = {vC.x, vC.y, vC.z, vC.w, vD.x, vD.y, vD.z, vD.w};
#pragma unroll
      for (int j = 0; j < 8; ++j)
        *(uint32_t*)&dV[(vcb + j) * 72 + vr2] = pk_rne(av[j], bv[j]);
      if (USE_BITS) {
#pragma unroll
        for (int g = 0; g < 4; ++g) mwc[g] = mwn[g];
      }
    }
  }
#pragma unroll
  for (int g = 0; g < 4; ++g)
#pragma unroll
    for (int r = 0; r < 4; ++r) {
      float inv = 1.0f / osum[g][r];
      float* dst = Op + (size_t)(q0w + g * 16 + quad * 4 + r) * DD + l15;
      dst[0]  = o[g][0][r] * inv;
      dst[16] = o[g][1][r] * inv;
      dst[32] = o[g][2][r] * inv;
      dst[48] = o[g][3][r] * inv;
    }
}

extern "C" void kernel_launch(void* const* d_in, const int* in_sizes, int n_in,
                              void* d_out, int out_size, void* d_ws, size_t ws_size,
                              hipStream_t stream) {
  const float* Q = (const float*)d_in[0];
  const float* K = (const float*)d_in[1];
  const float* V = (const float*)d_in[2];
  const int* M = (const int*)d_in[3];
  float* out = (float*)d_out;

  const size_t bits_bytes = (size_t)4 * SQ * SQ / 8;          // 2 MB
  const size_t kv_bytes = (size_t)64 * SQ * DD * 2;           // 16.78 MB each
  const size_t full_bytes = bits_bytes + 2 * kv_bytes;        // 35.65 MB

  if (ws_size >= full_bytes) {
    uint32_t* bits = (uint32_t*)d_ws;
    short* Kt = (short*)((char*)d_ws + bits_bytes);
    short* Vt = (short*)((char*)d_ws + bits_bytes + kv_bytes);
    pack_mask_kernel<<<2048, 256, 0, stream>>>(M, bits);
    prep_k_kernel<<<4096, 256, 0, stream>>>(K, Kt);   // 1,048,576 threads
    prep_v_kernel<<<8192, 256, 0, stream>>>(V, Vt);   // 2,097,152 threads
    attn_fast<<<4 * (SQ / 256) * 16, 256, 0, stream>>>(Q, Kt, Vt, bits, out);  // 512
  } else if (ws_size >= bits_bytes) {
    uint32_t* bits = (uint32_t*)d_ws;
    pack_mask_kernel<<<2048, 256, 0, stream>>>(M, bits);
    attn_fb<true><<<4 * (SQ / 256) * 16, 256, 0, stream>>>(Q, K, V, M, bits, out);
  } else {
    attn_fb<false><<<4 * (SQ / 256) * 16, 256, 0, stream>>>(Q, K, V, M, nullptr, out);
  }
}

// Round 8
// 276.644 us; speedup vs baseline: 1.0640x; 1.0640x over previous
//
#include <hip/hip_runtime.h>
#include <stdint.h>

// SparseAttentionAggregator: B=4 H=16 S=2048 D=64, fp32 in/out, mask [B,S,S] int32
// out = softmax((Q K^T)/8 masked_fill(mask==0,-1e9)) V
//
// R8 = R6 structure (g=2, 32 q-rows/wave, grid 1024 -> 4 blocks/CU, 16 waves/CU)
// + R7's LUT masking (acc init = plain NC; masked P zeroed on packed bf16 via
// AND with 16-entry LDS LUT). R7 post-mortem: g=4/grid-512 cost more (occupancy
// 20%) than its DS halving gained; the two optimizations are separable.

#define SQ 2048
#define DD 64

typedef __attribute__((ext_vector_type(8))) short short8;   // 8 bf16
typedef __attribute__((ext_vector_type(4))) short bshort4;  // 4 bf16
typedef __attribute__((ext_vector_type(4))) float f32x4;

union U8 { uint32_t u[4]; short8 s; };
union U4 { uint32_t u[2]; bshort4 s; };

__device__ __forceinline__ uint32_t pk_rne(float lo, float hi) {
  uint32_t a = __builtin_bit_cast(uint32_t, lo) + 0x8000u;
  uint32_t b = __builtin_bit_cast(uint32_t, hi) + 0x8000u;
  return __builtin_amdgcn_perm(b, a, 0x07060302u);
}
__device__ __forceinline__ uint32_t pk_tr(float lo, float hi) {
  return __builtin_amdgcn_perm(__builtin_bit_cast(uint32_t, hi),
                               __builtin_bit_cast(uint32_t, lo), 0x07060302u);
}

#if __has_builtin(__builtin_amdgcn_exp2f)
#define EXP2(x) __builtin_amdgcn_exp2f(x)
#else
#define EXP2(x) __exp2f(x)
#endif

__device__ __forceinline__ f32x4 mfma32(short8 a, short8 b, f32x4 c) {
  return __builtin_amdgcn_mfma_f32_16x16x32_bf16(a, b, c, 0, 0, 0);
}
#if __has_builtin(__builtin_amdgcn_mfma_f32_16x16x16bf16_1k)
__device__ __forceinline__ f32x4 mfma16(bshort4 a, bshort4 b, f32x4 c) {
  return __builtin_amdgcn_mfma_f32_16x16x16bf16_1k(a, b, c, 0, 0, 0);
}
#else
__device__ __forceinline__ f32x4 mfma16(bshort4 a, bshort4 b, f32x4 c) {
  asm("v_mfma_f32_16x16x16_bf16 %0, %1, %2, %0" : "+v"(c) : "v"(a), "v"(b));
  return c;
}
#endif

// async 16B/lane global->LDS; dest = base + lane*16
__device__ __forceinline__ void gload_lds16(const short* g, short* l) {
  __builtin_amdgcn_global_load_lds(
      (const __attribute__((address_space(1))) uint32_t*)g,
      (__attribute__((address_space(3))) uint32_t*)l, 16, 0, 0);
}

// ---- prep: mask bits (coalesced + ballot) ----
__global__ __launch_bounds__(256) void pack_mask_kernel(const int* __restrict__ m,
                                                        uint32_t* __restrict__ bits) {
  const int lane = threadIdx.x & 63;
  const int wid = (blockIdx.x * 256 + threadIdx.x) >> 6;
  const int nw = (gridDim.x * 256) >> 6;
  const size_t total = (size_t)4 * SQ * SQ;
  for (size_t base = (size_t)wid * 64; base < total; base += (size_t)nw * 64) {
    int v = m[base + lane];
    unsigned long long b = __ballot(v != 0);
    if (lane == 0) *(unsigned long long*)&bits[base >> 5] = b;
  }
}

// ---- prep: K -> fragment-ordered bf16 tiles (1,048,576 threads) ----
__global__ __launch_bounds__(256) void prep_k_kernel(const float* __restrict__ K,
                                                     short* __restrict__ Kt) {
  int tid = blockIdx.x * 256 + threadIdx.x;
  int l = tid & 63, rk = (tid >> 6) & 7, kt = (tid >> 9) & 31, bh = tid >> 14;
  if (bh >= 64) return;
  int key = kt * 64 + (rk >> 1) * 16 + (l & 15);
  int d0 = (rk & 1) * 32 + (l >> 4) * 8;
  const float* src = K + (size_t)bh * (SQ * DD) + (size_t)key * DD + d0;
  float4 a = ((const float4*)src)[0];
  float4 c = ((const float4*)src)[1];
  U8 w;
  w.u[0] = pk_rne(a.x, a.y); w.u[1] = pk_rne(a.z, a.w);
  w.u[2] = pk_rne(c.x, c.y); w.u[3] = pk_rne(c.z, c.w);
  *(short8*)(Kt + (size_t)tid * 8) = w.s;
}

// ---- prep: V^T -> fragment-ordered bf16 tiles (2,097,152 threads) ----
__global__ __launch_bounds__(256) void prep_v_kernel(const float* __restrict__ V,
                                                     short* __restrict__ Vt) {
  int tid = blockIdx.x * 256 + threadIdx.x;
  int r = tid & 63, rv = (tid >> 6) & 15, kt = (tid >> 10) & 31, bh = tid >> 15;
  if (bh >= 64) return;
  int d = (rv & 3) * 16 + (r & 15);
  int k0 = kt * 64 + (rv >> 2) * 16 + (r >> 4) * 4;
  const float* s = V + (size_t)bh * (SQ * DD) + (size_t)k0 * DD + d;
  U4 w;
  w.u[0] = pk_rne(s[0], s[DD]);
  w.u[1] = pk_rne(s[2 * DD], s[3 * DD]);
  *(bshort4*)(Vt + (size_t)tid * 4) = w.s;
}

// ---- fast attention: g=2, grid 1024, LUT masking, async staging ----
__global__ __launch_bounds__(256, 4) void attn_fast(
    const float* __restrict__ Qg, const short* __restrict__ Kt,
    const short* __restrict__ Vt, const uint32_t* __restrict__ bits,
    float* __restrict__ Og) {
  __shared__ __align__(16) short sK[2][4096];  // 8KB per buf, fragment order
  __shared__ __align__(16) short sV[2][4096];
  __shared__ __align__(8) uint32_t sLut[32];   // 16 x {m_lo, m_hi}

  const int tid = threadIdx.x;
  const int lane = tid & 63;
  const int wv = tid >> 6;
  const int l15 = lane & 15;
  const int quad = lane >> 4;

  const int bid = blockIdx.x;  // (b, qt, h), h innermost
  const int h = bid & 15;
  const int qt = (bid >> 4) & 15;
  const int b = bid >> 8;

  if (tid < 16) {  // mask LUT: bit r of index -> 0xFFFF half-mask
    uint32_t m0 = ((tid & 1) ? 0xFFFFu : 0u) | ((tid & 2) ? 0xFFFF0000u : 0u);
    uint32_t m1 = ((tid & 4) ? 0xFFFFu : 0u) | ((tid & 8) ? 0xFFFF0000u : 0u);
    sLut[tid * 2] = m0;
    sLut[tid * 2 + 1] = m1;
  }

  const size_t bh = (size_t)b * 16 + h;
  const float* Qp = Qg + bh * (size_t)(SQ * DD);
  const short* Kh = Kt + bh * (size_t)(SQ * DD);
  const short* Vh = Vt + bh * (size_t)(SQ * DD);
  float* Op = Og + bh * (size_t)(SQ * DD);
  const int q0w = qt * 128 + wv * 32;  // 32 q-rows/wave (2 groups)
  const int brow = b * SQ;

  const float QS = 0.18033688f;   // 0.125 * log2(e)
  const float NC = -17.312340f;   // -12 * log2(e)
  const f32x4 NCv = {NC, NC, NC, NC};

  U4 onesu; onesu.u[0] = 0x3f803f80u; onesu.u[1] = 0x3f803f80u;
  const bshort4 ones = onesu.s;

  // Q fragments (pre-scaled)
  short8 qf[2][2];
#pragma unroll
  for (int g = 0; g < 2; ++g)
#pragma unroll
    for (int dc = 0; dc < 2; ++dc) {
      const float* src = Qp + (size_t)(q0w + g * 16 + l15) * DD + dc * 32 + quad * 8;
      float4 a = *(const float4*)src;
      float4 c = *(const float4*)(src + 4);
      U8 t;
      t.u[0] = pk_rne(a.x * QS, a.y * QS);
      t.u[1] = pk_rne(a.z * QS, a.w * QS);
      t.u[2] = pk_rne(c.x * QS, c.y * QS);
      t.u[3] = pk_rne(c.z * QS, c.w * QS);
      qf[g][dc] = t.s;
    }

  f32x4 o[2][4];
  f32x4 osum[2];
#pragma unroll
  for (int g = 0; g < 2; ++g) {
#pragma unroll
    for (int dc = 0; dc < 4; ++dc) o[g][dc] = (f32x4){0.f, 0.f, 0.f, 0.f};
    osum[g] = (f32x4){0.f, 0.f, 0.f, 0.f};
  }

  // per-wave staging: 2 K-chunks + 2 V-chunks
  const int rk0 = wv * 2, rk1 = wv * 2 + 1;
  const short* kg0 = Kh + rk0 * 512 + lane * 8;  // +kt*4096 per tile
  const short* kg1 = Kh + rk1 * 512 + lane * 8;
  const short* vg0 = Vh + rk0 * 512 + lane * 8;
  const short* vg1 = Vh + rk1 * 512 + lane * 8;

  uint2 mwc[2], mwn[2];
#pragma unroll
  for (int g = 0; g < 2; ++g)
    mwc[g] = *(const uint2*)&bits[(size_t)(brow + q0w + g * 16 + l15) * (SQ / 32)];

  // prologue: stage tile 0 into buf 0
  gload_lds16(kg0, &sK[0][rk0 * 512]);
  gload_lds16(kg1, &sK[0][rk1 * 512]);
  gload_lds16(vg0, &sV[0][rk0 * 512]);
  gload_lds16(vg1, &sV[0][rk1 * 512]);

  const int sh0 = quad * 4;        // bit offsets for bfe
  const int sh1 = quad * 4 + 16;

  for (int kt = 0; kt < SQ / 64; ++kt) {
    const int buf = kt & 1;

    __syncthreads();  // buf loads complete; buf^1 readers done; sLut visible

    if (kt + 1 < SQ / 64) {  // async-stage next tile into buf^1
      const int off = (kt + 1) * 4096;
      gload_lds16(kg0 + off, &sK[buf ^ 1][rk0 * 512]);
      gload_lds16(kg1 + off, &sK[buf ^ 1][rk1 * 512]);
      gload_lds16(vg0 + off, &sV[buf ^ 1][rk0 * 512]);
      gload_lds16(vg1 + off, &sV[buf ^ 1][rk1 * 512]);
#pragma unroll
      for (int g = 0; g < 2; ++g)
        mwn[g] = *(const uint2*)&bits[(size_t)(brow + q0w + g * 16 + l15) * (SQ / 32) + (kt + 1) * 2];
    }

    const short* kb_base = &sK[buf][lane * 8];   // ds_read_b128 imm offsets
    const short* vb_base = &sV[buf][lane * 4];   // ds_read_b64 imm offsets

#pragma unroll
    for (int kb = 0; kb < 4; ++kb) {
      short8 kfa = *(const short8*)&kb_base[(kb * 2 + 0) * 512];
      short8 kfb = *(const short8*)&kb_base[(kb * 2 + 1) * 512];
      bshort4 vf[4];
#pragma unroll
      for (int dc = 0; dc < 4; ++dc)
        vf[dc] = *(const bshort4*)&vb_base[(kb * 4 + dc) * 256];
      const int sh = (kb & 1) ? sh1 : sh0;

#pragma unroll
      for (int g = 0; g < 2; ++g) {
        uint32_t w = (kb & 2) ? mwc[g].y : mwc[g].x;
        uint32_t t = (w >> sh) & 15u;              // v_bfe
        uint2 msk = *(const uint2*)&sLut[t * 2];   // ds_read_b64
        f32x4 st = mfma32(kfa, qf[g][0], NCv);
        st = mfma32(kfb, qf[g][1], st);
        float p0 = EXP2(st[0]);
        float p1 = EXP2(st[1]);
        float p2 = EXP2(st[2]);
        float p3 = EXP2(st[3]);
        U4 pw;
        pw.u[0] = pk_tr(p0, p1) & msk.x;  // zero masked halves exactly
        pw.u[1] = pk_tr(p2, p3) & msk.y;
#pragma unroll
        for (int dc = 0; dc < 4; ++dc)
          o[g][dc] = mfma16(pw.s, vf[dc], o[g][dc]);
        osum[g] = mfma16(pw.s, ones, osum[g]);
      }
    }

    if (kt + 1 < SQ / 64) {
#pragma unroll
      for (int g = 0; g < 2; ++g) mwc[g] = mwn[g];
    }
  }

  // epilogue: osum C/D layout == store layout; no shuffles
#pragma unroll
  for (int g = 0; g < 2; ++g)
#pragma unroll
    for (int r = 0; r < 4; ++r) {
      float inv = 1.0f / osum[g][r];
      float* dst = Op + (size_t)(q0w + g * 16 + quad * 4 + r) * DD + l15;
      dst[0]  = o[g][0][r] * inv;
      dst[16] = o[g][1][r] * inv;
      dst[32] = o[g][2][r] * inv;
      dst[48] = o[g][3][r] * inv;
    }
}

// ---- fallback (R3-winning structure) for small ws ----
template <bool USE_BITS>
__global__ __launch_bounds__(256, 2) void attn_fb(
    const float* __restrict__ Qg, const float* __restrict__ Kg,
    const float* __restrict__ Vg, const int* __restrict__ Mg,
    const uint32_t* __restrict__ bits, float* __restrict__ Og) {
  __shared__ __align__(16) short sK[2][64 * 72];
  __shared__ __align__(16) short sVT[2][64 * 72];
  const int tid = threadIdx.x;
  const int lane = tid & 63;
  const int wv = tid >> 6;
  const int l15 = lane & 15;
  const int quad = lane >> 4;
  const int bid = blockIdx.x;
  const int h = bid & 15;
  const int qt = (bid >> 4) & 7;
  const int b = bid >> 7;
  const size_t bh = (size_t)b * 16 + h;
  const float* Qp = Qg + bh * (size_t)(SQ * DD);
  const float* Kp = Kg + bh * (size_t)(SQ * DD);
  const float* Vp = Vg + bh * (size_t)(SQ * DD);
  float* Op = Og + bh * (size_t)(SQ * DD);
  const int q0w = qt * 256 + wv * 64;
  const int brow = b * SQ;
  const float QS = 0.18033688f, NC = -17.312340f;
  const float NINF = -__builtin_inff();
  U4 onesu; onesu.u[0] = 0x3f803f80u; onesu.u[1] = 0x3f803f80u;
  const bshort4 ones = onesu.s;
  short8 qf[4][2];
#pragma unroll
  for (int g = 0; g < 4; ++g)
#pragma unroll
    for (int dc = 0; dc < 2; ++dc) {
      const float* src = Qp + (size_t)(q0w + g * 16 + l15) * DD + dc * 32 + quad * 8;
      float4 a = *(const float4*)src;
      float4 c = *(const float4*)(src + 4);
      U8 t;
      t.u[0] = pk_rne(a.x * QS, a.y * QS); t.u[1] = pk_rne(a.z * QS, a.w * QS);
      t.u[2] = pk_rne(c.x * QS, c.y * QS); t.u[3] = pk_rne(c.z * QS, c.w * QS);
      qf[g][dc] = t.s;
    }
  f32x4 o[4][4]; f32x4 osum[4];
#pragma unroll
  for (int g = 0; g < 4; ++g) {
#pragma unroll
    for (int dc = 0; dc < 4; ++dc) o[g][dc] = (f32x4){0.f, 0.f, 0.f, 0.f};
    osum[g] = (f32x4){0.f, 0.f, 0.f, 0.f};
  }
  const int kr = lane, kcb = wv * 16;
  const int vr2 = (lane & 31) * 2, vcb = wv * 16 + (lane >> 5) * 8;
  const float* kbase = Kp + (size_t)kr * DD + kcb;
  const float* vbase = Vp + (size_t)vr2 * DD + vcb;
  float4 kA, kB, kC, kD, vA, vB, vC, vD;
  uint2 mwc[4], mwn[4];
  {
    const float4* kp = (const float4*)kbase;
    kA = kp[0]; kB = kp[1]; kC = kp[2]; kD = kp[3];
    const float* r0 = vbase;
    vA = ((const float4*)r0)[0]; vB = ((const float4*)r0)[1];
    vC = ((const float4*)(r0 + DD))[0]; vD = ((const float4*)(r0 + DD))[1];
    if (USE_BITS) {
#pragma unroll
      for (int g = 0; g < 4; ++g)
        mwc[g] = *(const uint2*)&bits[(size_t)(brow + q0w + g * 16 + l15) * (SQ / 32)];
    }
    U8 w0, w1;
    w0.u[0] = pk_rne(kA.x, kA.y); w0.u[1] = pk_rne(kA.z, kA.w);
    w0.u[2] = pk_rne(kB.x, kB.y); w0.u[3] = pk_rne(kB.z, kB.w);
    w1.u[0] = pk_rne(kC.x, kC.y); w1.u[1] = pk_rne(kC.z, kC.w);
    w1.u[2] = pk_rne(kD.x, kD.y); w1.u[3] = pk_rne(kD.z, kD.w);
    *(short8*)&sK[0][kr * 72 + kcb] = w0.s;
    *(short8*)&sK[0][kr * 72 + kcb + 8] = w1.s;
    float av[8] = {vA.x, vA.y, vA.z, vA.w, vB.x, vB.y, vB.z, vB.w};
    float bv[8] = {vC.x, vC.y, vC.z, vC.w, vD.x, vD.y, vD.z, vD.w};
#pragma unroll
    for (int j = 0; j < 8; ++j)
      *(uint32_t*)&sVT[0][(vcb + j) * 72 + vr2] = pk_rne(av[j], bv[j]);
  }
  for (int kt = 0; kt < SQ / 64; ++kt) {
    const int buf = kt & 1;
    const int k0 = kt * 64;
    __syncthreads();
    if (kt + 1 < SQ / 64) {
      const float4* kp = (const float4*)(kbase + (size_t)(k0 + 64) * DD);
      kA = kp[0]; kB = kp[1]; kC = kp[2]; kD = kp[3];
      const float* r0 = vbase + (size_t)(k0 + 64) * DD;
      vA = ((const float4*)r0)[0]; vB = ((const float4*)r0)[1];
      vC = ((const float4*)(r0 + DD))[0]; vD = ((const float4*)(r0 + DD))[1];
      if (USE_BITS) {
#pragma unroll
        for (int g = 0; g < 4; ++g)
          mwn[g] = *(const uint2*)&bits[(size_t)(brow + q0w + g * 16 + l15) * (SQ / 32) + (kt + 1) * 2];
      }
    }
    const short* sKb = sK[buf];
    const short* sVb = sVT[buf];
#pragma unroll
    for (int kb = 0; kb < 4; ++kb) {
      short8 kfa = *(const short8*)&sKb[(kb * 16 + l15) * 72 + quad * 8];
      short8 kfb = *(const short8*)&sKb[(kb * 16 + l15) * 72 + 32 + quad * 8];
      bshort4 vf[4];
#pragma unroll
      for (int dc = 0; dc < 4; ++dc)
        vf[dc] = *(const bshort4*)&sVb[(dc * 16 + l15) * 72 + kb * 16 + quad * 4];
#pragma unroll
      for (int g = 0; g < 4; ++g) {
        uint32_t t;
        if (USE_BITS) {
          uint32_t w = (kb & 2) ? mwc[g].y : mwc[g].x;
          t = w >> ((kb & 1) * 16 + quad * 4);
        } else {
          const int* mrow = Mg + (size_t)(brow + q0w + g * 16 + l15) * SQ + k0 + kb * 16 + quad * 4;
          t = (mrow[0] != 0) | ((mrow[1] != 0) << 1) | ((mrow[2] != 0) << 2) |
              ((mrow[3] != 0) << 3);
        }
        f32x4 ci;
        ci[0] = (t & 1) ? NC : NINF;
        ci[1] = (t & 2) ? NC : NINF;
        ci[2] = (t & 4) ? NC : NINF;
        ci[3] = (t & 8) ? NC : NINF;
        f32x4 st = mfma32(kfa, qf[g][0], ci);
        st = mfma32(kfb, qf[g][1], st);
        float p0 = EXP2(st[0]), p1 = EXP2(st[1]), p2 = EXP2(st[2]), p3 = EXP2(st[3]);
        U4 pw;
        pw.u[0] = pk_tr(p0, p1);
        pw.u[1] = pk_tr(p2, p3);
#pragma unroll
        for (int dc = 0; dc < 4; ++dc)
          o[g][dc] = mfma16(pw.s, vf[dc], o[g][dc]);
        osum[g] = mfma16(pw.s, ones, osum[g]);
      }
    }
    if (kt + 1 < SQ / 64) {
      short* dK = (short*)sK[buf ^ 1];
      short* dV = (short*)sVT[buf ^ 1];
      U8 w0, w1;
      w0.u[0] = pk_rne(kA.x, kA.y); w0.u[1] = pk_rne(kA.z, kA.w);
      w0.u[2] = pk_rne(kB.x, kB.y); w0.u[3] = pk_rne(kB.z, kB.w);
      w1.u[0] = pk_rne(kC.x, kC.y); w1.u[1] = pk_rne(kC.z, kC.w);
      w1.u[2] = pk_rne(kD.x, kD.y); w1.u[3] = pk_rne(kD.z, kD.w);
      *(short8*)&dK[kr * 72 + kcb] = w0.s;
      *(short8*)&dK[kr * 72 + kcb + 8] = w1.s;
      float av[8] = {vA.x, vA.y, vA.z, vA.w, vB.x, vB.y, vB.z, vB.w};
      float bv[8] = {vC.x, vC.y, vC.z, vC.w, vD.x, vD.y, vD.z, vD.w};
#pragma unroll
      for (int j = 0; j < 8; ++j)
        *(uint32_t*)&dV[(vcb + j) * 72 + vr2] = pk_rne(av[j], bv[j]);
      if (USE_BITS) {
#pragma unroll
        for (int g = 0; g < 4; ++g) mwc[g] = mwn[g];
      }
    }
  }
#pragma unroll
  for (int g = 0; g < 4; ++g)
#pragma unroll
    for (int r = 0; r < 4; ++r) {
      float inv = 1.0f / osum[g][r];
      float* dst = Op + (size_t)(q0w + g * 16 + quad * 4 + r) * DD + l15;
      dst[0]  = o[g][0][r] * inv;
      dst[16] = o[g][1][r] * inv;
      dst[32] = o[g][2][r] * inv;
      dst[48] = o[g][3][r] * inv;
    }
}

extern "C" void kernel_launch(void* const* d_in, const int* in_sizes, int n_in,
                              void* d_out, int out_size, void* d_ws, size_t ws_size,
                              hipStream_t stream) {
  const float* Q = (const float*)d_in[0];
  const float* K = (const float*)d_in[1];
  const float* V = (const float*)d_in[2];
  const int* M = (const int*)d_in[3];
  float* out = (float*)d_out;

  const size_t bits_bytes = (size_t)4 * SQ * SQ / 8;          // 2 MB
  const size_t kv_bytes = (size_t)64 * SQ * DD * 2;           // 16.78 MB each
  const size_t full_bytes = bits_bytes + 2 * kv_bytes;        // 35.65 MB

  if (ws_size >= full_bytes) {
    uint32_t* bits = (uint32_t*)d_ws;
    short* Kt = (short*)((char*)d_ws + bits_bytes);
    short* Vt = (short*)((char*)d_ws + bits_bytes + kv_bytes);
    pack_mask_kernel<<<2048, 256, 0, stream>>>(M, bits);
    prep_k_kernel<<<4096, 256, 0, stream>>>(K, Kt);   // 1,048,576 threads
    prep_v_kernel<<<8192, 256, 0, stream>>>(V, Vt);   // 2,097,152 threads
    attn_fast<<<4 * (SQ / 128) * 16, 256, 0, stream>>>(Q, Kt, Vt, bits, out);  // 1024
  } else if (ws_size >= bits_bytes) {
    uint32_t* bits = (uint32_t*)d_ws;
    pack_mask_kernel<<<2048, 256, 0, stream>>>(M, bits);
    attn_fb<true><<<4 * (SQ / 256) * 16, 256, 0, stream>>>(Q, K, V, M, bits, out);
  } else {
    attn_fb<false><<<4 * (SQ / 256) * 16, 256, 0, stream>>>(Q, K, V, M, nullptr, out);
  }
}

// Round 9
// 272.210 us; speedup vs baseline: 1.0814x; 1.0163x over previous
//
#include <hip/hip_runtime.h>
#include <stdint.h>

// SparseAttentionAggregator: B=4 H=16 S=2048 D=64, fp32 in/out, mask [B,S,S] int32
// out = softmax((Q K^T)/8 masked_fill(mask==0,-1e9)) V
//
// R9 = R8 + PV on mfma32 (16x16x32) via permuted-key Kt layout: within each
// 32-key group, sub-block A rows i <-> key (i>>2)*8+(i&3), sub-block B <-> +4,
// so the two QK^T score fragments concatenate into the exact 16x16x32 A-operand
// layout (m=q=l15, k=key=quad*8+j). PV: 5 mfma32 per (group,g) instead of 10
// mfma16; V frags one ds_read_b128 each. Mask bits: shifts quad*8 / quad*8+4.

#define SQ 2048
#define DD 64

typedef __attribute__((ext_vector_type(8))) short short8;   // 8 bf16
typedef __attribute__((ext_vector_type(4))) short bshort4;  // 4 bf16
typedef __attribute__((ext_vector_type(4))) float f32x4;

union U8 { uint32_t u[4]; short8 s; };
union U4 { uint32_t u[2]; bshort4 s; };

__device__ __forceinline__ uint32_t pk_rne(float lo, float hi) {
  uint32_t a = __builtin_bit_cast(uint32_t, lo) + 0x8000u;
  uint32_t b = __builtin_bit_cast(uint32_t, hi) + 0x8000u;
  return __builtin_amdgcn_perm(b, a, 0x07060302u);
}
__device__ __forceinline__ uint32_t pk_tr(float lo, float hi) {
  return __builtin_amdgcn_perm(__builtin_bit_cast(uint32_t, hi),
                               __builtin_bit_cast(uint32_t, lo), 0x07060302u);
}

#if __has_builtin(__builtin_amdgcn_exp2f)
#define EXP2(x) __builtin_amdgcn_exp2f(x)
#else
#define EXP2(x) __exp2f(x)
#endif

__device__ __forceinline__ f32x4 mfma32(short8 a, short8 b, f32x4 c) {
  return __builtin_amdgcn_mfma_f32_16x16x32_bf16(a, b, c, 0, 0, 0);
}
#if __has_builtin(__builtin_amdgcn_mfma_f32_16x16x16bf16_1k)
__device__ __forceinline__ f32x4 mfma16(bshort4 a, bshort4 b, f32x4 c) {
  return __builtin_amdgcn_mfma_f32_16x16x16bf16_1k(a, b, c, 0, 0, 0);
}
#else
__device__ __forceinline__ f32x4 mfma16(bshort4 a, bshort4 b, f32x4 c) {
  asm("v_mfma_f32_16x16x16_bf16 %0, %1, %2, %0" : "+v"(c) : "v"(a), "v"(b));
  return c;
}
#endif

// async 16B/lane global->LDS; dest = base + lane*16
__device__ __forceinline__ void gload_lds16(const short* g, short* l) {
  __builtin_amdgcn_global_load_lds(
      (const __attribute__((address_space(1))) uint32_t*)g,
      (__attribute__((address_space(3))) uint32_t*)l, 16, 0, 0);
}

// ---- prep: mask bits (coalesced + ballot) ----
__global__ __launch_bounds__(256) void pack_mask_kernel(const int* __restrict__ m,
                                                        uint32_t* __restrict__ bits) {
  const int lane = threadIdx.x & 63;
  const int wid = (blockIdx.x * 256 + threadIdx.x) >> 6;
  const int nw = (gridDim.x * 256) >> 6;
  const size_t total = (size_t)4 * SQ * SQ;
  for (size_t base = (size_t)wid * 64; base < total; base += (size_t)nw * 64) {
    int v = m[base + lane];
    unsigned long long b = __ballot(v != 0);
    if (lane == 0) *(unsigned long long*)&bits[base >> 5] = b;
  }
}

// ---- prep: K -> fragment-ordered bf16 tiles with permuted keys ----
// chunk rk = group*4 + sub*2 + half; row i = l&15 -> key offset within group
// = (i>>2)*8 + sub*4 + (i&3); d0 = half*32 + (l>>4)*8. 1,048,576 threads.
__global__ __launch_bounds__(256) void prep_k_kernel(const float* __restrict__ K,
                                                     short* __restrict__ Kt) {
  int tid = blockIdx.x * 256 + threadIdx.x;
  int l = tid & 63, rk = (tid >> 6) & 7, kt = (tid >> 9) & 31, bh = tid >> 14;
  if (bh >= 64) return;
  int group = rk >> 2, sub = (rk >> 1) & 1, half = rk & 1;
  int i = l & 15;
  int key = kt * 64 + group * 32 + (i >> 2) * 8 + sub * 4 + (i & 3);
  int d0 = half * 32 + (l >> 4) * 8;
  const float* src = K + (size_t)bh * (SQ * DD) + (size_t)key * DD + d0;
  float4 a = ((const float4*)src)[0];
  float4 c = ((const float4*)src)[1];
  U8 w;
  w.u[0] = pk_rne(a.x, a.y); w.u[1] = pk_rne(a.z, a.w);
  w.u[2] = pk_rne(c.x, c.y); w.u[3] = pk_rne(c.z, c.w);
  *(short8*)(Kt + (size_t)tid * 8) = w.s;
}

// ---- prep: V^T -> 16x16x32 B-operand layout ----
// chunk rv = group*4 + dc; lane l holds V[kt*64+group*32+(l>>4)*8+j][dc*16+(l&15)]
// j=0..7 -> short8. 1,048,576 threads (grid 4096).
__global__ __launch_bounds__(256) void prep_v_kernel(const float* __restrict__ V,
                                                     short* __restrict__ Vt) {
  int tid = blockIdx.x * 256 + threadIdx.x;
  int l = tid & 63, rv = (tid >> 6) & 7, kt = (tid >> 9) & 31, bh = tid >> 14;
  if (bh >= 64) return;
  int group = rv >> 2, dc = rv & 3;
  int d = dc * 16 + (l & 15);
  int key0 = kt * 64 + group * 32 + (l >> 4) * 8;
  const float* s = V + (size_t)bh * (SQ * DD) + (size_t)key0 * DD + d;
  U8 w;
  w.u[0] = pk_rne(s[0], s[DD]);
  w.u[1] = pk_rne(s[2 * DD], s[3 * DD]);
  w.u[2] = pk_rne(s[4 * DD], s[5 * DD]);
  w.u[3] = pk_rne(s[6 * DD], s[7 * DD]);
  *(short8*)(Vt + (size_t)tid * 8) = w.s;
}

// ---- fast attention: g=2, grid 1024, LUT masking, mfma32 PV ----
__global__ __launch_bounds__(256, 4) void attn_fast(
    const float* __restrict__ Qg, const short* __restrict__ Kt,
    const short* __restrict__ Vt, const uint32_t* __restrict__ bits,
    float* __restrict__ Og) {
  __shared__ __align__(16) short sK[2][4096];  // 8KB per buf, fragment order
  __shared__ __align__(16) short sV[2][4096];
  __shared__ __align__(8) uint32_t sLut[32];   // 16 x {m_lo, m_hi}

  const int tid = threadIdx.x;
  const int lane = tid & 63;
  const int wv = tid >> 6;
  const int l15 = lane & 15;
  const int quad = lane >> 4;

  const int bid = blockIdx.x;  // (b, qt, h), h innermost
  const int h = bid & 15;
  const int qt = (bid >> 4) & 15;
  const int b = bid >> 8;

  if (tid < 16) {  // mask LUT: bit r of index -> 0xFFFF half-mask
    uint32_t m0 = ((tid & 1) ? 0xFFFFu : 0u) | ((tid & 2) ? 0xFFFF0000u : 0u);
    uint32_t m1 = ((tid & 4) ? 0xFFFFu : 0u) | ((tid & 8) ? 0xFFFF0000u : 0u);
    sLut[tid * 2] = m0;
    sLut[tid * 2 + 1] = m1;
  }

  const size_t bh = (size_t)b * 16 + h;
  const float* Qp = Qg + bh * (size_t)(SQ * DD);
  const short* Kh = Kt + bh * (size_t)(SQ * DD);
  const short* Vh = Vt + bh * (size_t)(SQ * DD);
  float* Op = Og + bh * (size_t)(SQ * DD);
  const int q0w = qt * 128 + wv * 32;  // 32 q-rows/wave (2 groups)
  const int brow = b * SQ;

  const float QS = 0.18033688f;   // 0.125 * log2(e)
  const float NC = -17.312340f;   // -12 * log2(e)
  const f32x4 NCv = {NC, NC, NC, NC};

  U8 ones8u;
  ones8u.u[0] = 0x3f803f80u; ones8u.u[1] = 0x3f803f80u;
  ones8u.u[2] = 0x3f803f80u; ones8u.u[3] = 0x3f803f80u;
  const short8 ones8 = ones8u.s;

  // Q fragments (pre-scaled); A-layout content (m=l15, k=quad*8+j)
  short8 qf[2][2];
#pragma unroll
  for (int g = 0; g < 2; ++g)
#pragma unroll
    for (int dc = 0; dc < 2; ++dc) {
      const float* src = Qp + (size_t)(q0w + g * 16 + l15) * DD + dc * 32 + quad * 8;
      float4 a = *(const float4*)src;
      float4 c = *(const float4*)(src + 4);
      U8 t;
      t.u[0] = pk_rne(a.x * QS, a.y * QS);
      t.u[1] = pk_rne(a.z * QS, a.w * QS);
      t.u[2] = pk_rne(c.x * QS, c.y * QS);
      t.u[3] = pk_rne(c.z * QS, c.w * QS);
      qf[g][dc] = t.s;
    }

  f32x4 o[2][4];
  f32x4 osum[2];
#pragma unroll
  for (int g = 0; g < 2; ++g) {
#pragma unroll
    for (int dc = 0; dc < 4; ++dc) o[g][dc] = (f32x4){0.f, 0.f, 0.f, 0.f};
    osum[g] = (f32x4){0.f, 0.f, 0.f, 0.f};
  }

  // per-wave staging: 2 K-chunks + 2 V-chunks
  const int rk0 = wv * 2, rk1 = wv * 2 + 1;
  const short* kg0 = Kh + rk0 * 512 + lane * 8;  // +kt*4096 per tile
  const short* kg1 = Kh + rk1 * 512 + lane * 8;
  const short* vg0 = Vh + rk0 * 512 + lane * 8;
  const short* vg1 = Vh + rk1 * 512 + lane * 8;

  uint2 mwc[2], mwn[2];
#pragma unroll
  for (int g = 0; g < 2; ++g)
    mwc[g] = *(const uint2*)&bits[(size_t)(brow + q0w + g * 16 + l15) * (SQ / 32)];

  // prologue: stage tile 0 into buf 0
  gload_lds16(kg0, &sK[0][rk0 * 512]);
  gload_lds16(kg1, &sK[0][rk1 * 512]);
  gload_lds16(vg0, &sV[0][rk0 * 512]);
  gload_lds16(vg1, &sV[0][rk1 * 512]);

  const int shA = quad * 8;       // sub-A keys quad*8+{0..3}
  const int shB = quad * 8 + 4;   // sub-B keys quad*8+{4..7}

  for (int kt = 0; kt < SQ / 64; ++kt) {
    const int buf = kt & 1;

    __syncthreads();  // buf loads complete; buf^1 readers done; sLut visible

    if (kt + 1 < SQ / 64) {  // async-stage next tile into buf^1
      const int off = (kt + 1) * 4096;
      gload_lds16(kg0 + off, &sK[buf ^ 1][rk0 * 512]);
      gload_lds16(kg1 + off, &sK[buf ^ 1][rk1 * 512]);
      gload_lds16(vg0 + off, &sV[buf ^ 1][rk0 * 512]);
      gload_lds16(vg1 + off, &sV[buf ^ 1][rk1 * 512]);
#pragma unroll
      for (int g = 0; g < 2; ++g)
        mwn[g] = *(const uint2*)&bits[(size_t)(brow + q0w + g * 16 + l15) * (SQ / 32) + (kt + 1) * 2];
    }

    const short* kb_base = &sK[buf][lane * 8];   // ds_read_b128 imm offsets
    const short* vb_base = &sV[buf][lane * 8];

#pragma unroll
    for (int grp = 0; grp < 2; ++grp) {
      short8 kA0 = *(const short8*)&kb_base[(grp * 4 + 0) * 512];
      short8 kA1 = *(const short8*)&kb_base[(grp * 4 + 1) * 512];
      short8 kB0 = *(const short8*)&kb_base[(grp * 4 + 2) * 512];
      short8 kB1 = *(const short8*)&kb_base[(grp * 4 + 3) * 512];
      short8 vf[4];
#pragma unroll
      for (int dc = 0; dc < 4; ++dc)
        vf[dc] = *(const short8*)&vb_base[(grp * 4 + dc) * 512];

#pragma unroll
      for (int g = 0; g < 2; ++g) {
        uint32_t w = grp ? mwc[g].y : mwc[g].x;
        uint32_t tA = (w >> shA) & 15u;
        uint32_t tB = (w >> shB) & 15u;
        uint2 mskA = *(const uint2*)&sLut[tA * 2];  // ds_read_b64
        uint2 mskB = *(const uint2*)&sLut[tB * 2];
        // S^T sub-tiles: stA rows -> keys grp*32+quad*8+{0..3}, stB -> +4
        f32x4 stA = mfma32(kA0, qf[g][0], NCv);
        stA = mfma32(kA1, qf[g][1], stA);
        f32x4 stB = mfma32(kB0, qf[g][0], NCv);
        stB = mfma32(kB1, qf[g][1], stB);
        float pA0 = EXP2(stA[0]), pA1 = EXP2(stA[1]);
        float pA2 = EXP2(stA[2]), pA3 = EXP2(stA[3]);
        float pB0 = EXP2(stB[0]), pB1 = EXP2(stB[1]);
        float pB2 = EXP2(stB[2]), pB3 = EXP2(stB[3]);
        U8 pw;  // A-layout k=quad*8+j: j0..3 = sub-A, j4..7 = sub-B
        pw.u[0] = pk_tr(pA0, pA1) & mskA.x;
        pw.u[1] = pk_tr(pA2, pA3) & mskA.y;
        pw.u[2] = pk_tr(pB0, pB1) & mskB.x;
        pw.u[3] = pk_tr(pB2, pB3) & mskB.y;
#pragma unroll
        for (int dc = 0; dc < 4; ++dc)
          o[g][dc] = mfma32(pw.s, vf[dc], o[g][dc]);
        osum[g] = mfma32(pw.s, ones8, osum[g]);  // row sums on MFMA pipe
      }
    }

    if (kt + 1 < SQ / 64) {
#pragma unroll
      for (int g = 0; g < 2; ++g) mwc[g] = mwn[g];
    }
  }

  // epilogue: osum C/D layout == store layout; no shuffles
#pragma unroll
  for (int g = 0; g < 2; ++g)
#pragma unroll
    for (int r = 0; r < 4; ++r) {
      float inv = 1.0f / osum[g][r];
      float* dst = Op + (size_t)(q0w + g * 16 + quad * 4 + r) * DD + l15;
      dst[0]  = o[g][0][r] * inv;
      dst[16] = o[g][1][r] * inv;
      dst[32] = o[g][2][r] * inv;
      dst[48] = o[g][3][r] * inv;
    }
}

// ---- fallback (R3-winning structure) for small ws ----
template <bool USE_BITS>
__global__ __launch_bounds__(256, 2) void attn_fb(
    const float* __restrict__ Qg, const float* __restrict__ Kg,
    const float* __restrict__ Vg, const int* __restrict__ Mg,
    const uint32_t* __restrict__ bits, float* __restrict__ Og) {
  __shared__ __align__(16) short sK[2][64 * 72];
  __shared__ __align__(16) short sVT[2][64 * 72];
  const int tid = threadIdx.x;
  const int lane = tid & 63;
  const int wv = tid >> 6;
  const int l15 = lane & 15;
  const int quad = lane >> 4;
  const int bid = blockIdx.x;
  const int h = bid & 15;
  const int qt = (bid >> 4) & 7;
  const int b = bid >> 7;
  const size_t bh = (size_t)b * 16 + h;
  const float* Qp = Qg + bh * (size_t)(SQ * DD);
  const float* Kp = Kg + bh * (size_t)(SQ * DD);
  const float* Vp = Vg + bh * (size_t)(SQ * DD);
  float* Op = Og + bh * (size_t)(SQ * DD);
  const int q0w = qt * 256 + wv * 64;
  const int brow = b * SQ;
  const float QS = 0.18033688f, NC = -17.312340f;
  const float NINF = -__builtin_inff();
  U4 onesu; onesu.u[0] = 0x3f803f80u; onesu.u[1] = 0x3f803f80u;
  const bshort4 ones = onesu.s;
  short8 qf[4][2];
#pragma unroll
  for (int g = 0; g < 4; ++g)
#pragma unroll
    for (int dc = 0; dc < 2; ++dc) {
      const float* src = Qp + (size_t)(q0w + g * 16 + l15) * DD + dc * 32 + quad * 8;
      float4 a = *(const float4*)src;
      float4 c = *(const float4*)(src + 4);
      U8 t;
      t.u[0] = pk_rne(a.x * QS, a.y * QS); t.u[1] = pk_rne(a.z * QS, a.w * QS);
      t.u[2] = pk_rne(c.x * QS, c.y * QS); t.u[3] = pk_rne(c.z * QS, c.w * QS);
      qf[g][dc] = t.s;
    }
  f32x4 o[4][4]; f32x4 osum[4];
#pragma unroll
  for (int g = 0; g < 4; ++g) {
#pragma unroll
    for (int dc = 0; dc < 4; ++dc) o[g][dc] = (f32x4){0.f, 0.f, 0.f, 0.f};
    osum[g] = (f32x4){0.f, 0.f, 0.f, 0.f};
  }
  const int kr = lane, kcb = wv * 16;
  const int vr2 = (lane & 31) * 2, vcb = wv * 16 + (lane >> 5) * 8;
  const float* kbase = Kp + (size_t)kr * DD + kcb;
  const float* vbase = Vp + (size_t)vr2 * DD + vcb;
  float4 kA, kB, kC, kD, vA, vB, vC, vD;
  uint2 mwc[4], mwn[4];
  {
    const float4* kp = (const float4*)kbase;
    kA = kp[0]; kB = kp[1]; kC = kp[2]; kD = kp[3];
    const float* r0 = vbase;
    vA = ((const float4*)r0)[0]; vB = ((const float4*)r0)[1];
    vC = ((const float4*)(r0 + DD))[0]; vD = ((const float4*)(r0 + DD))[1];
    if (USE_BITS) {
#pragma unroll
      for (int g = 0; g < 4; ++g)
        mwc[g] = *(const uint2*)&bits[(size_t)(brow + q0w + g * 16 + l15) * (SQ / 32)];
    }
    U8 w0, w1;
    w0.u[0] = pk_rne(kA.x, kA.y); w0.u[1] = pk_rne(kA.z, kA.w);
    w0.u[2] = pk_rne(kB.x, kB.y); w0.u[3] = pk_rne(kB.z, kB.w);
    w1.u[0] = pk_rne(kC.x, kC.y); w1.u[1] = pk_rne(kC.z, kC.w);
    w1.u[2] = pk_rne(kD.x, kD.y); w1.u[3] = pk_rne(kD.z, kD.w);
    *(short8*)&sK[0][kr * 72 + kcb] = w0.s;
    *(short8*)&sK[0][kr * 72 + kcb + 8] = w1.s;
    float av[8] = {vA.x, vA.y, vA.z, vA.w, vB.x, vB.y, vB.z, vB.w};
    float bv[8] = {vC.x, vC.y, vC.z, vC.w, vD.x, vD.y, vD.z, vD.w};
#pragma unroll
    for (int j = 0; j < 8; ++j)
      *(uint32_t*)&sVT[0][(vcb + j) * 72 + vr2] = pk_rne(av[j], bv[j]);
  }
  for (int kt = 0; kt < SQ / 64; ++kt) {
    const int buf = kt & 1;
    const int k0 = kt * 64;
    __syncthreads();
    if (kt + 1 < SQ / 64) {
      const float4* kp = (const float4*)(kbase + (size_t)(k0 + 64) * DD);
      kA = kp[0]; kB = kp[1]; kC = kp[2]; kD = kp[3];
      const float* r0 = vbase + (size_t)(k0 + 64) * DD;
      vA = ((const float4*)r0)[0]; vB = ((const float4*)r0)[1];
      vC = ((const float4*)(r0 + DD))[0]; vD = ((const float4*)(r0 + DD))[1];
      if (USE_BITS) {
#pragma unroll
        for (int g = 0; g < 4; ++g)
          mwn[g] = *(const uint2*)&bits[(size_t)(brow + q0w + g * 16 + l15) * (SQ / 32) + (kt + 1) * 2];
      }
    }
    const short* sKb = sK[buf];
    const short* sVb = sVT[buf];
#pragma unroll
    for (int kb = 0; kb < 4; ++kb) {
      short8 kfa = *(const short8*)&sKb[(kb * 16 + l15) * 72 + quad * 8];
      short8 kfb = *(const short8*)&sKb[(kb * 16 + l15) * 72 + 32 + quad * 8];
      bshort4 vf[4];
#pragma unroll
      for (int dc = 0; dc < 4; ++dc)
        vf[dc] = *(const bshort4*)&sVb[(dc * 16 + l15) * 72 + kb * 16 + quad * 4];
#pragma unroll
      for (int g = 0; g < 4; ++g) {
        uint32_t t;
        if (USE_BITS) {
          uint32_t w = (kb & 2) ? mwc[g].y : mwc[g].x;
          t = w >> ((kb & 1) * 16 + quad * 4);
        } else {
          const int* mrow = Mg + (size_t)(brow + q0w + g * 16 + l15) * SQ + k0 + kb * 16 + quad * 4;
          t = (mrow[0] != 0) | ((mrow[1] != 0) << 1) | ((mrow[2] != 0) << 2) |
              ((mrow[3] != 0) << 3);
        }
        f32x4 ci;
        ci[0] = (t & 1) ? NC : NINF;
        ci[1] = (t & 2) ? NC : NINF;
        ci[2] = (t & 4) ? NC : NINF;
        ci[3] = (t & 8) ? NC : NINF;
        f32x4 st = mfma32(kfa, qf[g][0], ci);
        st = mfma32(kfb, qf[g][1], st);
        float p0 = EXP2(st[0]), p1 = EXP2(st[1]), p2 = EXP2(st[2]), p3 = EXP2(st[3]);
        U4 pw;
        pw.u[0] = pk_tr(p0, p1);
        pw.u[1] = pk_tr(p2, p3);
#pragma unroll
        for (int dc = 0; dc < 4; ++dc)
          o[g][dc] = mfma16(pw.s, vf[dc], o[g][dc]);
        osum[g] = mfma16(pw.s, ones, osum[g]);
      }
    }
    if (kt + 1 < SQ / 64) {
      short* dK = (short*)sK[buf ^ 1];
      short* dV = (short*)sVT[buf ^ 1];
      U8 w0, w1;
      w0.u[0] = pk_rne(kA.x, kA.y); w0.u[1] = pk_rne(kA.z, kA.w);
      w0.u[2] = pk_rne(kB.x, kB.y); w0.u[3] = pk_rne(kB.z, kB.w);
      w1.u[0] = pk_rne(kC.x, kC.y); w1.u[1] = pk_rne(kC.z, kC.w);
      w1.u[2] = pk_rne(kD.x, kD.y); w1.u[3] = pk_rne(kD.z, kD.w);
      *(short8*)&dK[kr * 72 + kcb] = w0.s;
      *(short8*)&dK[kr * 72 + kcb + 8] = w1.s;
      float av[8] = {vA.x, vA.y, vA.z, vA.w, vB.x, vB.y, vB.z, vB.w};
      float bv[8] = {vC.x, vC.y, vC.z, vC.w, vD.x, vD.y, vD.z, vD.w};
#pragma unroll
      for (int j = 0; j < 8; ++j)
        *(uint32_t*)&dV[(vcb + j) * 72 + vr2] = pk_rne(av[j], bv[j]);
      if (USE_BITS) {
#pragma unroll
        for (int g = 0; g < 4; ++g) mwc[g] = mwn[g];
      }
    }
  }
#pragma unroll
  for (int g = 0; g < 4; ++g)
#pragma unroll
    for (int r = 0; r < 4; ++r) {
      float inv = 1.0f / osum[g][r];
      float* dst = Op + (size_t)(q0w + g * 16 + quad * 4 + r) * DD + l15;
      dst[0]  = o[g][0][r] * inv;
      dst[16] = o[g][1][r] * inv;
      dst[32] = o[g][2][r] * inv;
      dst[48] = o[g][3][r] * inv;
    }
}

extern "C" void kernel_launch(void* const* d_in, const int* in_sizes, int n_in,
                              void* d_out, int out_size, void* d_ws, size_t ws_size,
                              hipStream_t stream) {
  const float* Q = (const float*)d_in[0];
  const float* K = (const float*)d_in[1];
  const float* V = (const float*)d_in[2];
  const int* M = (const int*)d_in[3];
  float* out = (float*)d_out;

  const size_t bits_bytes = (size_t)4 * SQ * SQ / 8;          // 2 MB
  const size_t kv_bytes = (size_t)64 * SQ * DD * 2;           // 16.78 MB each
  const size_t full_bytes = bits_bytes + 2 * kv_bytes;        // 35.65 MB

  if (ws_size >= full_bytes) {
    uint32_t* bits = (uint32_t*)d_ws;
    short* Kt = (short*)((char*)d_ws + bits_bytes);
    short* Vt = (short*)((char*)d_ws + bits_bytes + kv_bytes);
    pack_mask_kernel<<<2048, 256, 0, stream>>>(M, bits);
    prep_k_kernel<<<4096, 256, 0, stream>>>(K, Kt);   // 1,048,576 threads
    prep_v_kernel<<<4096, 256, 0, stream>>>(V, Vt);   // 1,048,576 threads
    attn_fast<<<4 * (SQ / 128) * 16, 256, 0, stream>>>(Q, Kt, Vt, bits, out);  // 1024
  } else if (ws_size >= bits_bytes) {
    uint32_t* bits = (uint32_t*)d_ws;
    pack_mask_kernel<<<2048, 256, 0, stream>>>(M, bits);
    attn_fb<true><<<4 * (SQ / 256) * 16, 256, 0, stream>>>(Q, K, V, M, bits, out);
  } else {
    attn_fb<false><<<4 * (SQ / 256) * 16, 256, 0, stream>>>(Q, K, V, M, nullptr, out);
  }
}